// Round 2
// baseline (454.252 us; speedup 1.0000x reference)
//
#include <hip/hip_runtime.h>

#define D    64
#define NIT  8        // Gauss-Seidel sweeps (residual << fp32 noise floor)
#define GRID 1024     // persistent 1-wave blocks; 4/CU (LDS-capped), 8 batches each

// Butcher coefficients
#define CA11 0.25f
#define CA12 -0.038675134594812866f   // 1/4 - sqrt(3)/6
#define CA21 0.5386751345948129f      // 1/4 + sqrt(3)/6
#define CA22 0.25f

typedef const __attribute__((address_space(1))) void* gas_p;
typedef __attribute__((address_space(3))) void*       las_p;

// Counted waits: N=16 == number of vmem ops we *intentionally* issue after the
// awaited buffer's 16 DMA loads. Compiler-added ops only make this more
// conservative (vmcnt waits oldest-first), never unsafe.
#define WAIT_VM16()  asm volatile("s_waitcnt vmcnt(16)" ::: "memory")
#define WAIT_LGKM0() asm volatile("s_waitcnt lgkmcnt(0)" ::: "memory")

// Persistent: one wave per block, grid-stride over batches. Per batch:
//   DMA(next A1,A2 -> LDS via global_load_lds) issued BEFORE the GS loop,
//   so 64 KB of loads+stores stay in flight under every compute phase.
__global__ __launch_bounds__(64, 1) void glrk_kernel(
    const float* __restrict__ A1, const float* __restrict__ A2,
    const float* __restrict__ y0, const float* __restrict__ hp,
    float* __restrict__ outy, float* __restrict__ oA1, float* __restrict__ oA2,
    int Btot)
{
    const int lane = threadIdx.x;   // 0..63

    // 16 KB per matrix, XOR-swizzled at float4 granularity: logical (r,c)
    // lives at group c ^ (r&7). global_load_lds writes linearly, so the
    // swizzle is applied on the per-lane GLOBAL source address (m173 pattern).
    __shared__ __align__(16) float P[D * D];
    __shared__ __align__(16) float Q[D * D];
    __shared__ __align__(16) float sV[2][D];

    const float h = *hp;

    // inst j stages rows j*4 .. j*4+3 (1 KB): lane -> (r = j*4 + (lane>>4),
    // c_p = lane&15), fetching global f4 r*16 + (c_p ^ (r&7)).
    // Each inst reads 4 dense 256-B segments -> perfectly coalesced.
    auto dma_matrix = [&](const float* __restrict__ src, float* __restrict__ buf) {
#pragma unroll
        for (int j = 0; j < 16; ++j) {
            const int r  = j * 4 + (lane >> 4);
            const int f4 = r * 16 + ((lane & 15) ^ (r & 7));
            __builtin_amdgcn_global_load_lds((gas_p)(src + f4 * 4),
                                             (las_p)(buf + j * 256), 16, 0, 0);
        }
    };

    int b = blockIdx.x;
    const int stride = gridDim.x;
    bool have = (b < Btot);
    if (have) {
        const size_t m = (size_t)b * (D * D);
        dma_matrix(A1 + m, P);      // 16 loads
        dma_matrix(A2 + m, Q);      // 16 loads
    }

    float4 rowA[16], rowB[16];
    const float4* v14 = (const float4*)sV[0];
    const float4* v24 = (const float4*)sV[1];

#pragma unroll 1
    while (have) {
        const int    bn        = b + stride;
        const bool   have_next = (bn < Btot);
        const size_t m         = (size_t)b * (D * D);

        const float y = y0[(size_t)b * D + lane];

        // ---- A1: P ready once the >=17 newer ops leave <=16 outstanding
        WAIT_VM16();
#pragma unroll
        for (int c = 0; c < 16; ++c)   // row-extract: beat-of-8 covers all 8 groups -> conflict-free
            rowA[c] = *(const float4*)&P[lane * 64 + ((c ^ (lane & 7)) * 4)];
        {
            float4* d4 = (float4*)(oA1 + m);   // dense coalesced copy-out, fire-and-forget
#pragma unroll
            for (int j = 0; j < 16; ++j) {
                const int s = j * 64 + lane;
                const int r = s >> 4;
                d4[s] = *(const float4*)&P[r * 64 + (((s & 15) ^ (r & 7)) * 4)];
            }
        }

        // ---- A2: Q ready (17 newer: y + 16 stores just issued)
        WAIT_VM16();
#pragma unroll
        for (int c = 0; c < 16; ++c)
            rowB[c] = *(const float4*)&Q[lane * 64 + ((c ^ (lane & 7)) * 4)];
        {
            float4* d4 = (float4*)(oA2 + m);
#pragma unroll
            for (int j = 0; j < 16; ++j) {
                const int s = j * 64 + lane;
                const int r = s >> 4;
                d4[s] = *(const float4*)&Q[r * 64 + (((s & 15) ^ (r & 7)) * 4)];
            }
        }

        // all ds_reads of P/Q must have executed before the DMA overwrites them
        WAIT_LGKM0();
        if (have_next) {
            const size_t mn = (size_t)bn * (D * D);
            dma_matrix(A1 + mn, P);
            dma_matrix(A2 + mn, Q);
        }

        // ---- Gauss-Seidel fixed point, wave-internal; next batch streams in
        // underneath (32 loads + ~32 stores in flight through this phase).
        float k1 = 0.f, k2 = 0.f;
#pragma unroll 1
        for (int it = 0; it < NIT; ++it) {
            sV[0][lane] = fmaf(h, fmaf(CA11, k1, CA12 * k2), y);
            __builtin_amdgcn_wave_barrier();
            float a0 = 0.f, a1 = 0.f, a2 = 0.f, a3 = 0.f;
#pragma unroll
            for (int c = 0; c < 16; ++c) {     // uniform-address LDS broadcast
                const float4 u = v14[c];
                a0 = fmaf(rowA[c].x, u.x, a0);
                a1 = fmaf(rowA[c].y, u.y, a1);
                a2 = fmaf(rowA[c].z, u.z, a2);
                a3 = fmaf(rowA[c].w, u.w, a3);
            }
            k1 = (a0 + a1) + (a2 + a3);

            sV[1][lane] = fmaf(h, fmaf(CA21, k1, CA22 * k2), y);
            __builtin_amdgcn_wave_barrier();
            float b0 = 0.f, b1 = 0.f, b2 = 0.f, b3 = 0.f;
#pragma unroll
            for (int c = 0; c < 16; ++c) {
                const float4 u = v24[c];
                b0 = fmaf(rowB[c].x, u.x, b0);
                b1 = fmaf(rowB[c].y, u.y, b1);
                b2 = fmaf(rowB[c].z, u.z, b2);
                b3 = fmaf(rowB[c].w, u.w, b3);
            }
            k2 = (b0 + b1) + (b2 + b3);
        }

        outy[(size_t)b * D + lane] = fmaf(h, 0.5f * (k1 + k2), y);

        b = bn; have = have_next;
    }
}

extern "C" void kernel_launch(void* const* d_in, const int* in_sizes, int n_in,
                              void* d_out, int out_size, void* d_ws, size_t ws_size,
                              hipStream_t stream) {
    const float* A1 = (const float*)d_in[0];
    const float* A2 = (const float*)d_in[1];
    const float* y0 = (const float*)d_in[2];
    const float* hp = (const float*)d_in[3];

    const int B = in_sizes[2] / D;  // y0 is (B, D)

    float* outy = (float*)d_out;            // B*D
    float* oA1  = outy + (size_t)B * D;     // B*D*D
    float* oA2  = oA1 + (size_t)B * D * D;  // B*D*D

    const int grid = (B < GRID) ? B : GRID;
    glrk_kernel<<<grid, 64, 0, stream>>>(A1, A2, y0, hp, outy, oA1, oA2, B);
}